// Round 15
// baseline (35.678 us; speedup 1.0000x reference)
//
#include <hip/hip_runtime.h>

// DRR via exact Siddon line integral — two-kernel form.
// K1 (setup): one thread per ray computes the world->voxel ray parameters
//   (s, sd, inv, amin, amax, raylen) ONCE (previously recomputed 32x per ray,
//   incl. 3 full-precision divides + sqrt) into d_ws as SoA; also zero-inits
//   out (replaces zero_out kernel).
// K2 (walk): R14's quad-cache + address/data-split loop. Block = 512 threads
//   = 8 waves = same 8x8 pixel patch at 8 alpha sub-ranges (SUBS 4->8 doubles
//   wave count to 25600 -> 3.1 fill rounds of the 32-wave/CU cap, smoothing
//   the ramp/tail that capped occupancy at 43%). Grid = 400 patches x 8
//   chunks; chunk in LOW 3 bits pins depth slab k to XCD k's L2. LDS-reduce
//   8 waves -> 1 atomic per ray per block (204.8K total, unchanged).
static constexpr float F_SDD = 1020.0f;
static constexpr int   DH = 160, DW = 160;       // detector H, W
static constexpr float DELX = 2.5f, DELY = 2.5f;
static constexpr int   VOL = 256;                // volume is VOL^3
static constexpr int   NRAY = DH * DW;
static constexpr int   TILES_X = DW / 8;         // 20
static constexpr int   TILES_Y = DH / 8;         // 20
static constexpr int   NTILE = TILES_X * TILES_Y;// 400
static constexpr int   CHUNKS = 8;               // depth chunks (== XCD count)
static constexpr int   SUBS = 8;                 // alpha sub-ranges (one per wave)
static constexpr int   KB = 4;                   // segments per batch
static constexpr float EPS = 1e-8f;

// d_ws SoA layout: 13 arrays of NRAY floats
// [0]=s0 [1]=s1 [2]=s2 [3]=sd0 [4]=sd1 [5]=sd2 [6]=inv0 [7]=inv1 [8]=inv2
// [9]=amin [10]=amax [11]=raylen [12]=unused/pad

extern "C" __global__ void __launch_bounds__(256)
drr_setup_kernel(const float* __restrict__ pose,   // [4][4] row-major
                 const float* __restrict__ ainv,   // [4][4] row-major
                 float* __restrict__ W,            // d_ws SoA
                 float* __restrict__ out)          // [NRAY] (zero-inited here)
{
    int ray = blockIdx.x * blockDim.x + threadIdx.x;
    if (ray >= NRAY) return;
    int py = ray / DW;
    int px = ray - py * DW;

    float xs = ((float)px - (DW - 1) * 0.5f) * DELX;
    float ys = ((float)py - (DH - 1) * 0.5f) * DELY;

    float R00 = pose[0], R01 = pose[1], R02 = pose[2],  t0 = pose[3];
    float R10 = pose[4], R11 = pose[5], R12 = pose[6],  t1 = pose[7];
    float R20 = pose[8], R21 = pose[9], R22 = pose[10], t2 = pose[11];

    float sw0 = t0, sw1 = t1, sw2 = t2;                       // src_w = R*0 + t
    float tw0 = R00 * xs + R01 * ys + R02 * F_SDD + t0;
    float tw1 = R10 * xs + R11 * ys + R12 * F_SDD + t1;
    float tw2 = R20 * xs + R21 * ys + R22 * F_SDD + t2;

    float dw0 = tw0 - sw0, dw1 = tw1 - sw1, dw2 = tw2 - sw2;
    float raylen = sqrtf(dw0 * dw0 + dw1 * dw1 + dw2 * dw2);

    float A00 = ainv[0], A01 = ainv[1], A02 = ainv[2],  A03 = ainv[3];
    float A10 = ainv[4], A11 = ainv[5], A12 = ainv[6],  A13 = ainv[7];
    float A20 = ainv[8], A21 = ainv[9], A22 = ainv[10], A23 = ainv[11];

    float s0 = A00 * sw0 + A01 * sw1 + A02 * sw2 + A03;
    float s1 = A10 * sw0 + A11 * sw1 + A12 * sw2 + A13;
    float s2 = A20 * sw0 + A21 * sw1 + A22 * sw2 + A23;
    float g0 = A00 * tw0 + A01 * tw1 + A02 * tw2 + A03;
    float g1 = A10 * tw0 + A11 * tw1 + A12 * tw2 + A13;
    float g2 = A20 * tw0 + A21 * tw1 + A22 * tw2 + A23;

    float sd0 = g0 - s0, sd1 = g1 - s1, sd2 = g2 - s2;
    float e0 = (fabsf(sd0) < EPS) ? EPS : sd0;
    float e1 = (fabsf(sd1) < EPS) ? EPS : sd1;
    float e2 = (fabsf(sd2) < EPS) ? EPS : sd2;
    float inv0 = 1.0f / e0, inv1 = 1.0f / e1, inv2 = 1.0f / e2;

    float lo0 = (0.0f - s0) * inv0, hi0 = ((float)VOL - s0) * inv0;
    float lo1 = (0.0f - s1) * inv1, hi1 = ((float)VOL - s1) * inv1;
    float lo2 = (0.0f - s2) * inv2, hi2 = ((float)VOL - s2) * inv2;
    float amin = fmaxf(fmaxf(fminf(lo0, hi0), fminf(lo1, hi1)), fminf(lo2, hi2));
    amin = fmaxf(amin, 0.0f);
    float amax = fminf(fminf(fmaxf(lo0, hi0), fmaxf(lo1, hi1)), fmaxf(lo2, hi2));
    amax = fminf(amax, 1.0f);
    amax = fmaxf(amax, amin);

    W[ray            ] = s0;   W[ray +  1 * NRAY] = s1;  W[ray +  2 * NRAY] = s2;
    W[ray +  3 * NRAY] = sd0;  W[ray +  4 * NRAY] = sd1; W[ray +  5 * NRAY] = sd2;
    W[ray +  6 * NRAY] = inv0; W[ray +  7 * NRAY] = inv1;W[ray +  8 * NRAY] = inv2;
    W[ray +  9 * NRAY] = amin; W[ray + 10 * NRAY] = amax;
    W[ray + 11 * NRAY] = raylen;
    out[ray] = 0.0f;
}

extern "C" __global__ void __launch_bounds__(512, 8)
drr_siddon_kernel(const float* __restrict__ density,
                  const float* __restrict__ W,      // d_ws SoA from setup
                  float* __restrict__ out)          // [NRAY]
{
    __shared__ float red[512];

    int chunk = blockIdx.x & (CHUNKS - 1);          // low bits -> XCD id
    int tile  = blockIdx.x >> 3;                    // CHUNKS == 8
    int tx = tile % TILES_X, ty = tile / TILES_X;

    int tid  = threadIdx.x;
    int sub  = tid >> 6;                            // wave index = alpha eighth
    int lane = tid & 63;

    // wave = 8x8 pixel patch at one alpha sub-range: lanes are NEIGHBORING
    // rays at the SAME alpha -> coherent gathers (i2 is the 4B-stride axis).
    int px = tx * 8 + (lane & 7);
    int py = ty * 8 + (lane >> 3);
    int ray = py * DW + px;

    float s0   = W[ray            ], s1   = W[ray +  1 * NRAY], s2   = W[ray +  2 * NRAY];
    float sd0  = W[ray +  3 * NRAY], sd1  = W[ray +  4 * NRAY], sd2  = W[ray +  5 * NRAY];
    float inv0 = W[ray +  6 * NRAY], inv1 = W[ray +  7 * NRAY], inv2 = W[ray +  8 * NRAY];
    float amin = W[ray +  9 * NRAY], amax = W[ray + 10 * NRAY];
    float raylen = W[ray + 11 * NRAY];

    // chunk sub-range, then this wave's exact eighth. Identical float math in
    // every block/thread of the same ray -> exact cover (no gaps/overlap).
    float arange  = amax - amin;
    float c_start = amin + arange * ((float)chunk * (1.0f / CHUNKS));
    float c_end   = (chunk == CHUNKS - 1) ? amax
                    : amin + arange * ((float)(chunk + 1) * (1.0f / CHUNKS));
    float crange  = c_end - c_start;
    float a_start = c_start + crange * ((float)sub * (1.0f / SUBS));
    float a_end   = (sub == SUBS - 1) ? c_end
                    : c_start + crange * ((float)(sub + 1) * (1.0f / SUBS));

    float da0 = fabsf(inv0), da1 = fabsf(inv1), da2 = fabsf(inv2);

    // per-axis walk state: next crossing alpha after a_start.
    float ax0, ax1, ax2;
    if (fabsf(sd0) < EPS) ax0 = 3.0e38f;
    else { float p = s0 + a_start * sd0;
           float kk = (sd0 > 0.0f) ? (floorf(p) + 1.0f) : (ceilf(p) - 1.0f);
           ax0 = (kk - s0) * inv0; }
    if (fabsf(sd1) < EPS) ax1 = 3.0e38f;
    else { float p = s1 + a_start * sd1;
           float kk = (sd1 > 0.0f) ? (floorf(p) + 1.0f) : (ceilf(p) - 1.0f);
           ax1 = (kk - s1) * inv1; }
    if (fabsf(sd2) < EPS) ax2 = 3.0e38f;
    else { float p = s2 + a_start * sd2;
           float kk = (sd2 > 0.0f) ? (floorf(p) + 1.0f) : (ceilf(p) - 1.0f);
           ax2 = (kk - s2) * inv2; }

    // batched segment walk, address/data split (R14-validated). Midpoint-
    // recomputed voxel index per segment (reference-exact); seg predicated to
    // 0 past a_end. clip(floor(p),0,255)==trunc(clamp(p,0,255)); flat index
    // c0*65536+c1*256+c2 exact in fp32. Per-lane aligned-float4 quad cache.
    float acc = 0.0f;
    float alpha = a_start;
    float4 quad = make_float4(0.f, 0.f, 0.f, 0.f);
    int qbase = -8;                                 // invalid -> first use loads
    while (alpha < a_end) {
        float  seg[KB];
        int    dsel[KB];
        bool   miss[KB];
        float4 ld[KB];
        // ---- phase A: addresses + issue cache-filtered loads ----
#pragma unroll
        for (int k = 0; k < KB; ++k) {
            float m     = fminf(fminf(ax0, ax1), ax2);   // v_min3
            float astop = fminf(m, a_end);
            float amid  = 0.5f * (alpha + astop);
            seg[k] = fmaxf(astop - alpha, 0.0f);
            float c0 = truncf(fminf(fmaxf(fmaf(amid, sd0, s0), 0.0f), 255.0f));
            float c1 = truncf(fminf(fmaxf(fmaf(amid, sd1, s1), 0.0f), 255.0f));
            float c2 = truncf(fminf(fmaxf(fmaf(amid, sd2, s2), 0.0f), 255.0f));
            int idx = (int)fmaf(c0, 65536.0f, fmaf(c1, 256.0f, c2));
            int d = idx - qbase;
            miss[k] = ((unsigned)d >= 4u);
            if (miss[k]) {                            // issue load, DON'T use
                qbase = idx & ~3;
                ld[k] = *(const float4*)(density + qbase);
                d = idx - qbase;
            }
            dsel[k] = d;
            if (ax0 <= m) ax0 += da0;
            if (ax1 <= m) ax1 += da1;
            if (ax2 <= m) ax2 += da2;
            alpha = m;
        }
        // ---- phase B: consume ----
#pragma unroll
        for (int k = 0; k < KB; ++k) {
            if (miss[k]) quad = ld[k];
            int d = dsel[k];
            float v = (d & 2) ? ((d & 1) ? quad.w : quad.z)
                              : ((d & 1) ? quad.y : quad.x);
            acc = fmaf(v, seg[k], acc);
        }
    }

    // combine the 8 wave partials for each ray in LDS, then one atomic.
    red[tid] = acc;
    __syncthreads();
    if (tid < 64) {
        float total = red[tid];
#pragma unroll
        for (int j = 1; j < SUBS; ++j) total += red[tid + j * 64];
        atomicAdd(&out[ray], total * raylen);
    }
}

extern "C" void kernel_launch(void* const* d_in, const int* in_sizes, int n_in,
                              void* d_out, int out_size, void* d_ws, size_t ws_size,
                              hipStream_t stream) {
    const float* density = (const float*)d_in[0];
    const float* pose    = (const float*)d_in[1];   // [1,4,4]
    const float* ainv    = (const float*)d_in[2];   // [4,4]
    float* out = (float*)d_out;                     // [1,1,160,160] flat
    float* W   = (float*)d_ws;                      // 13*NRAY floats = 1.33 MB

    hipLaunchKernelGGL(drr_setup_kernel, dim3((NRAY + 255) / 256), dim3(256),
                       0, stream, pose, ainv, W, out);

    dim3 block(512);
    dim3 grid(NTILE * CHUNKS);                      // 3200 blocks x 8 waves
    hipLaunchKernelGGL(drr_siddon_kernel, grid, block, 0, stream,
                       density, W, out);
}

// Round 16
// 32.493 us; speedup vs baseline: 1.0980x; 1.0980x over previous
//
#include <hip/hip_runtime.h>

// DRR via exact Siddon line integral — two-kernel form, R14 walk shell.
// K1 (setup, replaces zero_out): one thread per ray computes ray parameters
//   (s, sd, inv, amin, amax, raylen) ONCE — previously recomputed 32x per ray
//   (8 chunks x 4 subs), incl. 3 full-precision divides + sqrt — into d_ws
//   SoA; also zero-inits out. Formulas textually identical to R14's preamble
//   -> bit-identical values -> identical partition and walk.
// K2 (walk): EXACTLY R14's validated structure: block = 256 threads = 4 waves
//   = 8x8 pixel patch at 4 alpha sub-ranges; grid = 400 patches x 8 chunks,
//   chunk in LOW 3 bits pins depth slab k to XCD k's L2; per-lane float4 quad
//   cache + KB=4 address/data phase split; LDS-reduce -> 1 atomic/ray/block.
static constexpr float F_SDD = 1020.0f;
static constexpr int   DH = 160, DW = 160;       // detector H, W
static constexpr float DELX = 2.5f, DELY = 2.5f;
static constexpr int   VOL = 256;                // volume is VOL^3
static constexpr int   NRAY = DH * DW;
static constexpr int   TILES_X = DW / 8;         // 20
static constexpr int   TILES_Y = DH / 8;         // 20
static constexpr int   NTILE = TILES_X * TILES_Y;// 400
static constexpr int   CHUNKS = 8;               // depth chunks (== XCD count)
static constexpr int   SUBS = 4;                 // alpha sub-ranges (one per wave)
static constexpr int   KB = 4;                   // segments per batch
static constexpr float EPS = 1e-8f;

// d_ws SoA layout: 12 arrays of NRAY floats
// [0]=s0 [1]=s1 [2]=s2 [3]=sd0 [4]=sd1 [5]=sd2 [6]=inv0 [7]=inv1 [8]=inv2
// [9]=amin [10]=amax [11]=raylen

extern "C" __global__ void __launch_bounds__(256)
drr_setup_kernel(const float* __restrict__ pose,   // [4][4] row-major
                 const float* __restrict__ ainv,   // [4][4] row-major
                 float* __restrict__ W,            // d_ws SoA
                 float* __restrict__ out)          // [NRAY] (zero-inited here)
{
    int ray = blockIdx.x * blockDim.x + threadIdx.x;
    if (ray >= NRAY) return;
    int py = ray / DW;
    int px = ray - py * DW;

    float xs = ((float)px - (DW - 1) * 0.5f) * DELX;
    float ys = ((float)py - (DH - 1) * 0.5f) * DELY;

    float R00 = pose[0], R01 = pose[1], R02 = pose[2],  t0 = pose[3];
    float R10 = pose[4], R11 = pose[5], R12 = pose[6],  t1 = pose[7];
    float R20 = pose[8], R21 = pose[9], R22 = pose[10], t2 = pose[11];

    float sw0 = t0, sw1 = t1, sw2 = t2;                       // src_w = R*0 + t
    float tw0 = R00 * xs + R01 * ys + R02 * F_SDD + t0;
    float tw1 = R10 * xs + R11 * ys + R12 * F_SDD + t1;
    float tw2 = R20 * xs + R21 * ys + R22 * F_SDD + t2;

    float dw0 = tw0 - sw0, dw1 = tw1 - sw1, dw2 = tw2 - sw2;
    float raylen = sqrtf(dw0 * dw0 + dw1 * dw1 + dw2 * dw2);

    float A00 = ainv[0], A01 = ainv[1], A02 = ainv[2],  A03 = ainv[3];
    float A10 = ainv[4], A11 = ainv[5], A12 = ainv[6],  A13 = ainv[7];
    float A20 = ainv[8], A21 = ainv[9], A22 = ainv[10], A23 = ainv[11];

    float s0 = A00 * sw0 + A01 * sw1 + A02 * sw2 + A03;
    float s1 = A10 * sw0 + A11 * sw1 + A12 * sw2 + A13;
    float s2 = A20 * sw0 + A21 * sw1 + A22 * sw2 + A23;
    float g0 = A00 * tw0 + A01 * tw1 + A02 * tw2 + A03;
    float g1 = A10 * tw0 + A11 * tw1 + A12 * tw2 + A13;
    float g2 = A20 * tw0 + A21 * tw1 + A22 * tw2 + A23;

    float sd0 = g0 - s0, sd1 = g1 - s1, sd2 = g2 - s2;
    float e0 = (fabsf(sd0) < EPS) ? EPS : sd0;
    float e1 = (fabsf(sd1) < EPS) ? EPS : sd1;
    float e2 = (fabsf(sd2) < EPS) ? EPS : sd2;
    float inv0 = 1.0f / e0, inv1 = 1.0f / e1, inv2 = 1.0f / e2;

    float lo0 = (0.0f - s0) * inv0, hi0 = ((float)VOL - s0) * inv0;
    float lo1 = (0.0f - s1) * inv1, hi1 = ((float)VOL - s1) * inv1;
    float lo2 = (0.0f - s2) * inv2, hi2 = ((float)VOL - s2) * inv2;
    float amin = fmaxf(fmaxf(fminf(lo0, hi0), fminf(lo1, hi1)), fminf(lo2, hi2));
    amin = fmaxf(amin, 0.0f);
    float amax = fminf(fminf(fmaxf(lo0, hi0), fmaxf(lo1, hi1)), fmaxf(lo2, hi2));
    amax = fminf(amax, 1.0f);
    amax = fmaxf(amax, amin);

    W[ray            ] = s0;   W[ray +  1 * NRAY] = s1;   W[ray +  2 * NRAY] = s2;
    W[ray +  3 * NRAY] = sd0;  W[ray +  4 * NRAY] = sd1;  W[ray +  5 * NRAY] = sd2;
    W[ray +  6 * NRAY] = inv0; W[ray +  7 * NRAY] = inv1; W[ray +  8 * NRAY] = inv2;
    W[ray +  9 * NRAY] = amin; W[ray + 10 * NRAY] = amax;
    W[ray + 11 * NRAY] = raylen;
    out[ray] = 0.0f;
}

extern "C" __global__ void __launch_bounds__(256, 8)
drr_siddon_kernel(const float* __restrict__ density,
                  const float* __restrict__ W,      // d_ws SoA from setup
                  float* __restrict__ out)          // [NRAY]
{
    __shared__ float red[256];

    int chunk = blockIdx.x & (CHUNKS - 1);          // low bits -> XCD id
    int tile  = blockIdx.x >> 3;                    // CHUNKS == 8
    int tx = tile % TILES_X, ty = tile / TILES_X;

    int tid  = threadIdx.x;
    int sub  = tid >> 6;                            // wave index = alpha quarter
    int lane = tid & 63;

    // wave = 8x8 pixel patch at one alpha sub-range: lanes are NEIGHBORING
    // rays at the SAME alpha -> coherent gathers (i2 is the 4B-stride axis).
    int px = tx * 8 + (lane & 7);
    int py = ty * 8 + (lane >> 3);
    int ray = py * DW + px;

    float s0   = W[ray            ], s1   = W[ray +  1 * NRAY], s2   = W[ray +  2 * NRAY];
    float sd0  = W[ray +  3 * NRAY], sd1  = W[ray +  4 * NRAY], sd2  = W[ray +  5 * NRAY];
    float inv0 = W[ray +  6 * NRAY], inv1 = W[ray +  7 * NRAY], inv2 = W[ray +  8 * NRAY];
    float amin = W[ray +  9 * NRAY], amax = W[ray + 10 * NRAY];
    float raylen = W[ray + 11 * NRAY];

    // chunk sub-range, then this wave's exact quarter. Identical float math in
    // every block/thread of the same ray -> exact cover (no gaps/overlap).
    float arange  = amax - amin;
    float c_start = amin + arange * ((float)chunk * (1.0f / CHUNKS));
    float c_end   = (chunk == CHUNKS - 1) ? amax
                    : amin + arange * ((float)(chunk + 1) * (1.0f / CHUNKS));
    float crange  = c_end - c_start;
    float a_start = c_start + crange * ((float)sub * (1.0f / SUBS));
    float a_end   = (sub == SUBS - 1) ? c_end
                    : c_start + crange * ((float)(sub + 1) * (1.0f / SUBS));

    float da0 = fabsf(inv0), da1 = fabsf(inv1), da2 = fabsf(inv2);

    // per-axis walk state: next crossing alpha after a_start.
    float ax0, ax1, ax2;
    if (fabsf(sd0) < EPS) ax0 = 3.0e38f;
    else { float p = s0 + a_start * sd0;
           float kk = (sd0 > 0.0f) ? (floorf(p) + 1.0f) : (ceilf(p) - 1.0f);
           ax0 = (kk - s0) * inv0; }
    if (fabsf(sd1) < EPS) ax1 = 3.0e38f;
    else { float p = s1 + a_start * sd1;
           float kk = (sd1 > 0.0f) ? (floorf(p) + 1.0f) : (ceilf(p) - 1.0f);
           ax1 = (kk - s1) * inv1; }
    if (fabsf(sd2) < EPS) ax2 = 3.0e38f;
    else { float p = s2 + a_start * sd2;
           float kk = (sd2 > 0.0f) ? (floorf(p) + 1.0f) : (ceilf(p) - 1.0f);
           ax2 = (kk - s2) * inv2; }

    // batched segment walk, address/data split (R14-validated). Midpoint-
    // recomputed voxel index per segment (reference-exact); seg predicated to
    // 0 past a_end. clip(floor(p),0,255)==trunc(clamp(p,0,255)); flat index
    // c0*65536+c1*256+c2 exact in fp32. Per-lane aligned-float4 quad cache.
    float acc = 0.0f;
    float alpha = a_start;
    float4 quad = make_float4(0.f, 0.f, 0.f, 0.f);
    int qbase = -8;                                 // invalid -> first use loads
    while (alpha < a_end) {
        float  seg[KB];
        int    dsel[KB];
        bool   miss[KB];
        float4 ld[KB];
        // ---- phase A: addresses + issue cache-filtered loads ----
#pragma unroll
        for (int k = 0; k < KB; ++k) {
            float m     = fminf(fminf(ax0, ax1), ax2);   // v_min3
            float astop = fminf(m, a_end);
            float amid  = 0.5f * (alpha + astop);
            seg[k] = fmaxf(astop - alpha, 0.0f);
            float c0 = truncf(fminf(fmaxf(fmaf(amid, sd0, s0), 0.0f), 255.0f));
            float c1 = truncf(fminf(fmaxf(fmaf(amid, sd1, s1), 0.0f), 255.0f));
            float c2 = truncf(fminf(fmaxf(fmaf(amid, sd2, s2), 0.0f), 255.0f));
            int idx = (int)fmaf(c0, 65536.0f, fmaf(c1, 256.0f, c2));
            int d = idx - qbase;
            miss[k] = ((unsigned)d >= 4u);
            if (miss[k]) {                            // issue load, DON'T use
                qbase = idx & ~3;
                ld[k] = *(const float4*)(density + qbase);
                d = idx - qbase;
            }
            dsel[k] = d;
            if (ax0 <= m) ax0 += da0;
            if (ax1 <= m) ax1 += da1;
            if (ax2 <= m) ax2 += da2;
            alpha = m;
        }
        // ---- phase B: consume ----
#pragma unroll
        for (int k = 0; k < KB; ++k) {
            if (miss[k]) quad = ld[k];
            int d = dsel[k];
            float v = (d & 2) ? ((d & 1) ? quad.w : quad.z)
                              : ((d & 1) ? quad.y : quad.x);
            acc = fmaf(v, seg[k], acc);
        }
    }

    // combine the 4 wave partials for each ray in LDS, then one atomic.
    red[tid] = acc;
    __syncthreads();
    if (tid < 64) {
        float total = red[tid] + red[tid + 64] + red[tid + 128] + red[tid + 192];
        atomicAdd(&out[ray], total * raylen);
    }
}

extern "C" void kernel_launch(void* const* d_in, const int* in_sizes, int n_in,
                              void* d_out, int out_size, void* d_ws, size_t ws_size,
                              hipStream_t stream) {
    const float* density = (const float*)d_in[0];
    const float* pose    = (const float*)d_in[1];   // [1,4,4]
    const float* ainv    = (const float*)d_in[2];   // [4,4]
    float* out = (float*)d_out;                     // [1,1,160,160] flat
    float* W   = (float*)d_ws;                      // 12*NRAY floats = 1.23 MB

    hipLaunchKernelGGL(drr_setup_kernel, dim3((NRAY + 255) / 256), dim3(256),
                       0, stream, pose, ainv, W, out);

    dim3 block(256);
    dim3 grid(NTILE * CHUNKS);                      // 3200 blocks x 4 waves
    hipLaunchKernelGGL(drr_siddon_kernel, grid, block, 0, stream,
                       density, W, out);
}

// Round 17
// 29.612 us; speedup vs baseline: 1.2048x; 1.0973x over previous
//
#include <hip/hip_runtime.h>

// DRR via exact Siddon line integral — R14 (best: 28.85us) + longest-first
// tile dispatch order. Corner-tile rays cross ~40% more voxel planes than
// center tiles (lateral drift adds |di0|+|di1| to the ~256 i2-crossings);
// with 12.5 blocks/CU demand vs the 8-block residency cap (1.56 fill rounds),
// dispatching long tiles first puts the SHORT tiles in the drain round.
// tile -> (tx,ty) via outside-in interleave: 0,19,1,18,... per axis.
// Everything else is R14 byte-for-byte: block = 256 threads = 4 waves = 8x8
// pixel patch at 4 alpha sub-ranges; grid = 400 patches x 8 depth chunks,
// chunk in LOW 3 bits pins depth slab k to XCD k's L2 (round-robin dispatch);
// per-lane float4 quad cache + KB=4 address/data phase split; LDS-reduce ->
// 1 atomic per ray per block.
static constexpr float F_SDD = 1020.0f;
static constexpr int   DH = 160, DW = 160;       // detector H, W
static constexpr float DELX = 2.5f, DELY = 2.5f;
static constexpr int   VOL = 256;                // volume is VOL^3
static constexpr int   NRAY = DH * DW;
static constexpr int   TILES_X = DW / 8;         // 20
static constexpr int   TILES_Y = DH / 8;         // 20
static constexpr int   NTILE = TILES_X * TILES_Y;// 400
static constexpr int   CHUNKS = 8;               // depth chunks (== XCD count)
static constexpr int   SUBS = 4;                 // alpha sub-ranges (one per wave)
static constexpr int   KB = 4;                   // segments per batch
static constexpr float EPS = 1e-8f;

extern "C" __global__ void zero_out_kernel(float* __restrict__ out, int n) {
    int i = blockIdx.x * blockDim.x + threadIdx.x;
    if (i < n) out[i] = 0.0f;
}

extern "C" __global__ void __launch_bounds__(256, 8)
drr_siddon_kernel(const float* __restrict__ density,
                  const float* __restrict__ pose,   // [4][4] row-major
                  const float* __restrict__ ainv,   // [4][4] row-major
                  float* __restrict__ out)          // [NRAY]
{
    __shared__ float red[256];

    int chunk = blockIdx.x & (CHUNKS - 1);          // low bits -> XCD id
    int tile  = blockIdx.x >> 3;                    // CHUNKS == 8

    // longest-first dispatch: outer tiles (long rays) first, center last.
    int u = tile % TILES_X, v = tile / TILES_X;
    int tx = (u & 1) ? (TILES_X - 1 - (u >> 1)) : (u >> 1);
    int ty = (v & 1) ? (TILES_Y - 1 - (v >> 1)) : (v >> 1);

    int tid  = threadIdx.x;
    int sub  = tid >> 6;                            // wave index = alpha quarter
    int lane = tid & 63;

    // wave = 8x8 pixel patch at one alpha sub-range: lanes are NEIGHBORING
    // rays at the SAME alpha -> coherent gathers (i2 is the 4B-stride axis).
    int px = tx * 8 + (lane & 7);
    int py = ty * 8 + (lane >> 3);
    int ray = py * DW + px;

    // Detector-plane target in camera frame (source at origin).
    float xs = ((float)px - (DW - 1) * 0.5f) * DELX;
    float ys = ((float)py - (DH - 1) * 0.5f) * DELY;

    // pose: rows of [R | t]
    float R00 = pose[0], R01 = pose[1], R02 = pose[2],  t0 = pose[3];
    float R10 = pose[4], R11 = pose[5], R12 = pose[6],  t1 = pose[7];
    float R20 = pose[8], R21 = pose[9], R22 = pose[10], t2 = pose[11];

    float sw0 = t0, sw1 = t1, sw2 = t2;                       // src_w = R*0 + t
    float tw0 = R00 * xs + R01 * ys + R02 * F_SDD + t0;
    float tw1 = R10 * xs + R11 * ys + R12 * F_SDD + t1;
    float tw2 = R20 * xs + R21 * ys + R22 * F_SDD + t2;

    float dw0 = tw0 - sw0, dw1 = tw1 - sw1, dw2 = tw2 - sw2;
    float raylen = sqrtf(dw0 * dw0 + dw1 * dw1 + dw2 * dw2);

    // world -> voxel
    float A00 = ainv[0], A01 = ainv[1], A02 = ainv[2],  A03 = ainv[3];
    float A10 = ainv[4], A11 = ainv[5], A12 = ainv[6],  A13 = ainv[7];
    float A20 = ainv[8], A21 = ainv[9], A22 = ainv[10], A23 = ainv[11];

    float s0 = A00 * sw0 + A01 * sw1 + A02 * sw2 + A03;
    float s1 = A10 * sw0 + A11 * sw1 + A12 * sw2 + A13;
    float s2 = A20 * sw0 + A21 * sw1 + A22 * sw2 + A23;
    float g0 = A00 * tw0 + A01 * tw1 + A02 * tw2 + A03;
    float g1 = A10 * tw0 + A11 * tw1 + A12 * tw2 + A13;
    float g2 = A20 * tw0 + A21 * tw1 + A22 * tw2 + A23;

    float sd0 = g0 - s0, sd1 = g1 - s1, sd2 = g2 - s2;
    float e0 = (fabsf(sd0) < EPS) ? EPS : sd0;
    float e1 = (fabsf(sd1) < EPS) ? EPS : sd1;
    float e2 = (fabsf(sd2) < EPS) ? EPS : sd2;
    float inv0 = 1.0f / e0, inv1 = 1.0f / e1, inv2 = 1.0f / e2;

    // bbox entry/exit in alpha, clamped to the [0,1] segment
    float lo0 = (0.0f - s0) * inv0, hi0 = ((float)VOL - s0) * inv0;
    float lo1 = (0.0f - s1) * inv1, hi1 = ((float)VOL - s1) * inv1;
    float lo2 = (0.0f - s2) * inv2, hi2 = ((float)VOL - s2) * inv2;
    float amin = fmaxf(fmaxf(fminf(lo0, hi0), fminf(lo1, hi1)), fminf(lo2, hi2));
    amin = fmaxf(amin, 0.0f);
    float amax = fminf(fminf(fmaxf(lo0, hi0), fmaxf(lo1, hi1)), fmaxf(lo2, hi2));
    amax = fminf(amax, 1.0f);
    amax = fmaxf(amax, amin);

    // chunk sub-range, then this wave's exact quarter. Identical float math in
    // every block/thread of the same ray -> exact cover (no gaps/overlap).
    float arange  = amax - amin;
    float c_start = amin + arange * ((float)chunk * (1.0f / CHUNKS));
    float c_end   = (chunk == CHUNKS - 1) ? amax
                    : amin + arange * ((float)(chunk + 1) * (1.0f / CHUNKS));
    float crange  = c_end - c_start;
    float a_start = c_start + crange * ((float)sub * (1.0f / SUBS));
    float a_end   = (sub == SUBS - 1) ? c_end
                    : c_start + crange * ((float)(sub + 1) * (1.0f / SUBS));

    // per-axis walk state: next crossing alpha after a_start, per-crossing
    // alpha increment.
    float ax0, ax1, ax2, da0, da1, da2;
    if (fabsf(sd0) < EPS) { ax0 = 3.0e38f; da0 = 0.0f; }
    else {
        float p = s0 + a_start * sd0;
        float k = (sd0 > 0.0f) ? (floorf(p) + 1.0f) : (ceilf(p) - 1.0f);
        ax0 = (k - s0) * inv0; da0 = fabsf(inv0);
    }
    if (fabsf(sd1) < EPS) { ax1 = 3.0e38f; da1 = 0.0f; }
    else {
        float p = s1 + a_start * sd1;
        float k = (sd1 > 0.0f) ? (floorf(p) + 1.0f) : (ceilf(p) - 1.0f);
        ax1 = (k - s1) * inv1; da1 = fabsf(inv1);
    }
    if (fabsf(sd2) < EPS) { ax2 = 3.0e38f; da2 = 0.0f; }
    else {
        float p = s2 + a_start * sd2;
        float k = (sd2 > 0.0f) ? (floorf(p) + 1.0f) : (ceilf(p) - 1.0f);
        ax2 = (k - s2) * inv2; da2 = fabsf(inv2);
    }

    // batched segment walk, address/data split (R14-validated). Midpoint-
    // recomputed voxel index per segment (reference-exact); seg predicated to
    // 0 past a_end. clip(floor(p),0,255)==trunc(clamp(p,0,255)); flat index
    // c0*65536+c1*256+c2 exact in fp32. Per-lane aligned-float4 quad cache.
    float acc = 0.0f;
    float alpha = a_start;
    float4 quad = make_float4(0.f, 0.f, 0.f, 0.f);
    int qbase = -8;                                 // invalid -> first use loads
    while (alpha < a_end) {
        float  seg[KB];
        int    dsel[KB];
        bool   miss[KB];
        float4 ld[KB];
        // ---- phase A: addresses + issue cache-filtered loads ----
#pragma unroll
        for (int k = 0; k < KB; ++k) {
            float m     = fminf(fminf(ax0, ax1), ax2);   // v_min3
            float astop = fminf(m, a_end);
            float amid  = 0.5f * (alpha + astop);
            seg[k] = fmaxf(astop - alpha, 0.0f);
            float c0 = truncf(fminf(fmaxf(fmaf(amid, sd0, s0), 0.0f), 255.0f));
            float c1 = truncf(fminf(fmaxf(fmaf(amid, sd1, s1), 0.0f), 255.0f));
            float c2 = truncf(fminf(fmaxf(fmaf(amid, sd2, s2), 0.0f), 255.0f));
            int idx = (int)fmaf(c0, 65536.0f, fmaf(c1, 256.0f, c2));
            int d = idx - qbase;
            miss[k] = ((unsigned)d >= 4u);
            if (miss[k]) {                            // issue load, DON'T use
                qbase = idx & ~3;
                ld[k] = *(const float4*)(density + qbase);
                d = idx - qbase;
            }
            dsel[k] = d;
            if (ax0 <= m) ax0 += da0;
            if (ax1 <= m) ax1 += da1;
            if (ax2 <= m) ax2 += da2;
            alpha = m;
        }
        // ---- phase B: consume ----
#pragma unroll
        for (int k = 0; k < KB; ++k) {
            if (miss[k]) quad = ld[k];
            int d = dsel[k];
            float v = (d & 2) ? ((d & 1) ? quad.w : quad.z)
                              : ((d & 1) ? quad.y : quad.x);
            acc = fmaf(v, seg[k], acc);
        }
    }

    // combine the 4 wave partials for each ray in LDS, then one atomic.
    red[tid] = acc;
    __syncthreads();
    if (tid < 64) {
        float total = red[tid] + red[tid + 64] + red[tid + 128] + red[tid + 192];
        atomicAdd(&out[ray], total * raylen);
    }
}

extern "C" void kernel_launch(void* const* d_in, const int* in_sizes, int n_in,
                              void* d_out, int out_size, void* d_ws, size_t ws_size,
                              hipStream_t stream) {
    const float* density = (const float*)d_in[0];
    const float* pose    = (const float*)d_in[1];   // [1,4,4]
    const float* ainv    = (const float*)d_in[2];   // [4,4]
    float* out = (float*)d_out;                     // [1,1,160,160] flat

    hipLaunchKernelGGL(zero_out_kernel, dim3((NRAY + 255) / 256), dim3(256), 0,
                       stream, out, NRAY);

    dim3 block(256);
    dim3 grid(NTILE * CHUNKS);                      // 3200 blocks
    hipLaunchKernelGGL(drr_siddon_kernel, grid, block, 0, stream,
                       density, pose, ainv, out);
}

// Round 19
// 28.730 us; speedup vs baseline: 1.2418x; 1.0307x over previous
//
#include <hip/hip_runtime.h>

// DRR via exact Siddon line integral — R14 (best measured: 28.85us).
// Per-lane float4 quad cache + KB=4 address/data phase split.
// Shell: block = 256 threads = 4 waves; wave = 8x8 pixel patch at one of 4
// alpha sub-ranges. Grid = 400 patches x 8 depth chunks; chunk in the LOW 3
// bits of blockIdx pins depth slab k to XCD k's L2 (round-robin dispatch).
// LDS-reduce -> 1 atomic per ray per block.
static constexpr float F_SDD = 1020.0f;
static constexpr int   DH = 160, DW = 160;       // detector H, W
static constexpr float DELX = 2.5f, DELY = 2.5f;
static constexpr int   VOL = 256;                // volume is VOL^3
static constexpr int   NRAY = DH * DW;
static constexpr int   TILES_X = DW / 8;         // 20
static constexpr int   TILES_Y = DH / 8;         // 20
static constexpr int   NTILE = TILES_X * TILES_Y;// 400
static constexpr int   CHUNKS = 8;               // depth chunks (== XCD count)
static constexpr int   SUBS = 4;                 // alpha sub-ranges (one per wave)
static constexpr int   KB = 4;                   // segments per batch
static constexpr float EPS = 1e-8f;

extern "C" __global__ void zero_out_kernel(float* __restrict__ out, int n) {
    int i = blockIdx.x * blockDim.x + threadIdx.x;
    if (i < n) out[i] = 0.0f;
}

extern "C" __global__ void __launch_bounds__(256, 8)
drr_siddon_kernel(const float* __restrict__ density,
                  const float* __restrict__ pose,   // [4][4] row-major
                  const float* __restrict__ ainv,   // [4][4] row-major
                  float* __restrict__ out)          // [NRAY]
{
    __shared__ float red[256];

    int chunk = blockIdx.x & (CHUNKS - 1);          // low bits -> XCD id
    int tile  = blockIdx.x >> 3;                    // CHUNKS == 8
    int tx = tile % TILES_X, ty = tile / TILES_X;

    int tid  = threadIdx.x;
    int sub  = tid >> 6;                            // wave index = alpha quarter
    int lane = tid & 63;

    // wave = 8x8 pixel patch at one alpha sub-range: lanes are NEIGHBORING
    // rays at the SAME alpha -> coherent gathers (i2 is the 4B-stride axis).
    int px = tx * 8 + (lane & 7);
    int py = ty * 8 + (lane >> 3);
    int ray = py * DW + px;

    // Detector-plane target in camera frame (source at origin).
    float xs = ((float)px - (DW - 1) * 0.5f) * DELX;
    float ys = ((float)py - (DH - 1) * 0.5f) * DELY;

    // pose: rows of [R | t]
    float R00 = pose[0], R01 = pose[1], R02 = pose[2],  t0 = pose[3];
    float R10 = pose[4], R11 = pose[5], R12 = pose[6],  t1 = pose[7];
    float R20 = pose[8], R21 = pose[9], R22 = pose[10], t2 = pose[11];

    float sw0 = t0, sw1 = t1, sw2 = t2;                       // src_w = R*0 + t
    float tw0 = R00 * xs + R01 * ys + R02 * F_SDD + t0;
    float tw1 = R10 * xs + R11 * ys + R12 * F_SDD + t1;
    float tw2 = R20 * xs + R21 * ys + R22 * F_SDD + t2;

    float dw0 = tw0 - sw0, dw1 = tw1 - sw1, dw2 = tw2 - sw2;
    float raylen = sqrtf(dw0 * dw0 + dw1 * dw1 + dw2 * dw2);

    // world -> voxel
    float A00 = ainv[0], A01 = ainv[1], A02 = ainv[2],  A03 = ainv[3];
    float A10 = ainv[4], A11 = ainv[5], A12 = ainv[6],  A13 = ainv[7];
    float A20 = ainv[8], A21 = ainv[9], A22 = ainv[10], A23 = ainv[11];

    float s0 = A00 * sw0 + A01 * sw1 + A02 * sw2 + A03;
    float s1 = A10 * sw0 + A11 * sw1 + A12 * sw2 + A13;
    float s2 = A20 * sw0 + A21 * sw1 + A22 * sw2 + A23;
    float g0 = A00 * tw0 + A01 * tw1 + A02 * tw2 + A03;
    float g1 = A10 * tw0 + A11 * tw1 + A12 * tw2 + A13;
    float g2 = A20 * tw0 + A21 * tw1 + A22 * tw2 + A23;

    float sd0 = g0 - s0, sd1 = g1 - s1, sd2 = g2 - s2;
    float e0 = (fabsf(sd0) < EPS) ? EPS : sd0;
    float e1 = (fabsf(sd1) < EPS) ? EPS : sd1;
    float e2 = (fabsf(sd2) < EPS) ? EPS : sd2;
    float inv0 = 1.0f / e0, inv1 = 1.0f / e1, inv2 = 1.0f / e2;

    // bbox entry/exit in alpha, clamped to the [0,1] segment
    float lo0 = (0.0f - s0) * inv0, hi0 = ((float)VOL - s0) * inv0;
    float lo1 = (0.0f - s1) * inv1, hi1 = ((float)VOL - s1) * inv1;
    float lo2 = (0.0f - s2) * inv2, hi2 = ((float)VOL - s2) * inv2;
    float amin = fmaxf(fmaxf(fminf(lo0, hi0), fminf(lo1, hi1)), fminf(lo2, hi2));
    amin = fmaxf(amin, 0.0f);
    float amax = fminf(fminf(fmaxf(lo0, hi0), fmaxf(lo1, hi1)), fmaxf(lo2, hi2));
    amax = fminf(amax, 1.0f);
    amax = fmaxf(amax, amin);

    // chunk sub-range, then this wave's exact quarter. Identical float math in
    // every block/thread of the same ray -> exact cover (no gaps/overlap).
    float arange  = amax - amin;
    float c_start = amin + arange * ((float)chunk * (1.0f / CHUNKS));
    float c_end   = (chunk == CHUNKS - 1) ? amax
                    : amin + arange * ((float)(chunk + 1) * (1.0f / CHUNKS));
    float crange  = c_end - c_start;
    float a_start = c_start + crange * ((float)sub * (1.0f / SUBS));
    float a_end   = (sub == SUBS - 1) ? c_end
                    : c_start + crange * ((float)(sub + 1) * (1.0f / SUBS));

    // per-axis walk state: next crossing alpha after a_start, per-crossing
    // alpha increment.
    float ax0, ax1, ax2, da0, da1, da2;
    if (fabsf(sd0) < EPS) { ax0 = 3.0e38f; da0 = 0.0f; }
    else {
        float p = s0 + a_start * sd0;
        float k = (sd0 > 0.0f) ? (floorf(p) + 1.0f) : (ceilf(p) - 1.0f);
        ax0 = (k - s0) * inv0; da0 = fabsf(inv0);
    }
    if (fabsf(sd1) < EPS) { ax1 = 3.0e38f; da1 = 0.0f; }
    else {
        float p = s1 + a_start * sd1;
        float k = (sd1 > 0.0f) ? (floorf(p) + 1.0f) : (ceilf(p) - 1.0f);
        ax1 = (k - s1) * inv1; da1 = fabsf(inv1);
    }
    if (fabsf(sd2) < EPS) { ax2 = 3.0e38f; da2 = 0.0f; }
    else {
        float p = s2 + a_start * sd2;
        float k = (sd2 > 0.0f) ? (floorf(p) + 1.0f) : (ceilf(p) - 1.0f);
        ax2 = (k - s2) * inv2; da2 = fabsf(inv2);
    }

    // batched segment walk, address/data split. Midpoint-recomputed voxel
    // index per segment (reference-exact, no error propagation); seg
    // predicated to 0 past a_end. clip(floor(p),0,255)==trunc(clamp(p,0,255));
    // flat index c0*65536+c1*256+c2 exact in fp32. Per-lane float4 quad cache.
    float acc = 0.0f;
    float alpha = a_start;
    float4 quad = make_float4(0.f, 0.f, 0.f, 0.f);
    int qbase = -8;                                 // invalid -> first use loads
    while (alpha < a_end) {
        float  seg[KB];
        int    dsel[KB];
        bool   miss[KB];
        float4 ld[KB];
        // ---- phase A: addresses + issue cache-filtered loads ----
#pragma unroll
        for (int k = 0; k < KB; ++k) {
            float m     = fminf(fminf(ax0, ax1), ax2);   // v_min3
            float astop = fminf(m, a_end);
            float amid  = 0.5f * (alpha + astop);
            seg[k] = fmaxf(astop - alpha, 0.0f);
            float c0 = truncf(fminf(fmaxf(fmaf(amid, sd0, s0), 0.0f), 255.0f));
            float c1 = truncf(fminf(fmaxf(fmaf(amid, sd1, s1), 0.0f), 255.0f));
            float c2 = truncf(fminf(fmaxf(fmaf(amid, sd2, s2), 0.0f), 255.0f));
            int idx = (int)fmaf(c0, 65536.0f, fmaf(c1, 256.0f, c2));
            int d = idx - qbase;
            miss[k] = ((unsigned)d >= 4u);
            if (miss[k]) {                            // issue load, DON'T use
                qbase = idx & ~3;
                ld[k] = *(const float4*)(density + qbase);
                d = idx - qbase;
            }
            dsel[k] = d;
            if (ax0 <= m) ax0 += da0;
            if (ax1 <= m) ax1 += da1;
            if (ax2 <= m) ax2 += da2;
            alpha = m;
        }
        // ---- phase B: consume ----
#pragma unroll
        for (int k = 0; k < KB; ++k) {
            if (miss[k]) quad = ld[k];
            int d = dsel[k];
            float v = (d & 2) ? ((d & 1) ? quad.w : quad.z)
                              : ((d & 1) ? quad.y : quad.x);
            acc = fmaf(v, seg[k], acc);
        }
    }

    // combine the 4 wave partials for each ray in LDS, then one atomic.
    red[tid] = acc;
    __syncthreads();
    if (tid < 64) {
        float total = red[tid] + red[tid + 64] + red[tid + 128] + red[tid + 192];
        atomicAdd(&out[ray], total * raylen);
    }
}

extern "C" void kernel_launch(void* const* d_in, const int* in_sizes, int n_in,
                              void* d_out, int out_size, void* d_ws, size_t ws_size,
                              hipStream_t stream) {
    const float* density = (const float*)d_in[0];
    const float* pose    = (const float*)d_in[1];   // [1,4,4]
    const float* ainv    = (const float*)d_in[2];   // [4,4]
    float* out = (float*)d_out;                     // [1,1,160,160] flat

    hipLaunchKernelGGL(zero_out_kernel, dim3((NRAY + 255) / 256), dim3(256), 0,
                       stream, out, NRAY);

    dim3 block(256);
    dim3 grid(NTILE * CHUNKS);                      // 3200 blocks
    hipLaunchKernelGGL(drr_siddon_kernel, grid, block, 0, stream,
                       density, pose, ainv, out);
}